// Round 1
// baseline (243.659 us; speedup 1.0000x reference)
//
#include <hip/hip_runtime.h>
#include <hip/hip_bf16.h>

typedef __bf16 bf16;
typedef __bf16 bf16x4 __attribute__((ext_vector_type(4)));
typedef __bf16 bf16x8 __attribute__((ext_vector_type(8)));
typedef float  f32x4  __attribute__((ext_vector_type(4)));

// Problem constants: B=16, T=1024, C=512, H=8, Dh=64
#define BB 16
#define TT 1024
#define CC 512
#define HH 8
#define DH 64

__device__ __forceinline__ void gload16(const void* gsrc, void* ldst) {
    // async global->LDS, 16B per lane; LDS dest must be wave-uniform base (HW adds lane*16)
    __builtin_amdgcn_global_load_lds(
        (const __attribute__((address_space(1))) void*)gsrc,
        (__attribute__((address_space(3))) void*)ldst, 16, 0, 0);
}

__device__ __forceinline__ f32x4 mfma16(bf16x8 a, bf16x8 b, f32x4 c) {
    return __builtin_amdgcn_mfma_f32_16x16x32_bf16(a, b, c, 0, 0, 0);
}

// ---------------- conversion kernels ----------------
__global__ void k_cvt(const float* __restrict__ src, bf16* __restrict__ dst, int n) {
    int i = (blockIdx.x * blockDim.x + threadIdx.x) * 4;
    if (i < n) {
        float4 v = *(const float4*)(src + i);
        bf16x4 o = { (bf16)v.x, (bf16)v.y, (bf16)v.z, (bf16)v.w };
        *(bf16x4*)(dst + i) = o;
    }
}

// src[K][N] (row-major) -> dst[N][K] (row-major), i.e. store B^T for gemm_bt
__global__ void k_cvt_t(const float* __restrict__ src, bf16* __restrict__ dst, int K, int N) {
    int idx = blockIdx.x * blockDim.x + threadIdx.x;
    if (idx < K * N) {
        int k = idx / N, n = idx - k * N;
        dst[(size_t)n * K + k] = (bf16)src[idx];
    }
}

// ---------------- GEMM: C[M,N] = A[M,K] * Bt[N,K]^T ----------------
// m97 structure: 128x128 tile, BK=32, 4 waves (2x2), 16x16x32 bf16 MFMA.
// MODE 0: write fp32 to outF[M,N].  MODE 1: QKV scatter epilogue.
template<int MODE>
__global__ __launch_bounds__(256)
void k_gemm_bt(const bf16* __restrict__ A, const bf16* __restrict__ Bt,
               int M, int N, int K,
               float* __restrict__ outF,
               bf16* __restrict__ qb, bf16* __restrict__ kb, bf16* __restrict__ vtb)
{
    __shared__ bf16 sA[128 * 32];
    __shared__ bf16 sB[128 * 32];
    const int tid  = threadIdx.x;
    const int wid  = tid >> 6;
    const int lane = tid & 63;
    const int l15  = lane & 15, l4 = lane >> 4;

    const int nNt = N >> 7;
    const int mt  = blockIdx.x / nNt;
    const int nt  = blockIdx.x - mt * nNt;
    const int m0  = mt << 7, n0 = nt << 7;
    const int wr  = (wid >> 1) * 64, wc = (wid & 1) * 64;

    f32x4 zero = {0.f, 0.f, 0.f, 0.f};
    f32x4 acc[4][4];
#pragma unroll
    for (int i = 0; i < 4; ++i)
#pragma unroll
        for (int j = 0; j < 4; ++j) acc[i][j] = zero;

    // per-wave staging: 2 chunks of 1KB (=16 tile rows) for each of A and B
    const int soff0 = wid * 1024;          // element offset of this wave's chunk 0
    const int soff1 = soff0 + 512;
    const int e0 = soff0 + lane * 8;
    const int e1 = soff1 + lane * 8;
    const int r0 = e0 >> 5, c0 = e0 & 31;
    const int r1 = e1 >> 5, c1 = e1 & 31;

    for (int k0 = 0; k0 < K; k0 += 32) {
        gload16(A  + (size_t)(m0 + r0) * K + k0 + c0, sA + soff0);
        gload16(A  + (size_t)(m0 + r1) * K + k0 + c1, sA + soff1);
        gload16(Bt + (size_t)(n0 + r0) * K + k0 + c0, sB + soff0);
        gload16(Bt + (size_t)(n0 + r1) * K + k0 + c1, sB + soff1);
        __syncthreads();
        bf16x8 af[4], bfr[4];
#pragma unroll
        for (int i = 0; i < 4; ++i)
            af[i] = *(const bf16x8*)(sA + (wr + i * 16 + l15) * 32 + l4 * 8);
#pragma unroll
        for (int j = 0; j < 4; ++j)
            bfr[j] = *(const bf16x8*)(sB + (wc + j * 16 + l15) * 32 + l4 * 8);
#pragma unroll
        for (int i = 0; i < 4; ++i)
#pragma unroll
            for (int j = 0; j < 4; ++j)
                acc[i][j] = mfma16(af[i], bfr[j], acc[i][j]);
        __syncthreads();
    }

#pragma unroll
    for (int i = 0; i < 4; ++i) {
#pragma unroll
        for (int j = 0; j < 4; ++j) {
#pragma unroll
            for (int rg = 0; rg < 4; ++rg) {
                int rm = m0 + wr + i * 16 + l4 * 4 + rg;
                int cn = n0 + wc + j * 16 + l15;
                float v = acc[i][j][rg];
                if (MODE == 0) {
                    outF[(size_t)rm * N + cn] = v;
                } else {
                    // rm = b*T + t ; cn = s*C + h*Dh + d
                    int b = rm >> 10, t = rm & 1023;
                    int s = cn >> 9, h = (cn >> 6) & 7, d = cn & 63;
                    size_t bh = (size_t)(b * HH + h);
                    bf16 bv = (bf16)v;
                    if (s == 0)      qb [(bh * TT + t) * DH + d] = bv;   // Q [bh][t][d]
                    else if (s == 1) kb [(bh * TT + t) * DH + d] = bv;   // K [bh][t][d]
                    else             vtb[(bh * DH + d) * TT + t] = bv;   // V^T [bh][d][t]
                }
            }
        }
    }
}

// ---------------- flash attention (causal) ----------------
// grid: 128 bh * 8 qtiles ; block: 4 waves, each wave owns 32 q-rows.
__global__ __launch_bounds__(256)
void k_attn(const bf16* __restrict__ qg, const bf16* __restrict__ kg,
            const bf16* __restrict__ vtg, bf16* __restrict__ yb)
{
    __shared__ bf16 pl[4][32 * 40];   // per-wave P tile, rows padded to 40 elems (80B)
    const int tid = threadIdx.x, w = tid >> 6, lane = tid & 63;
    const int l15 = lane & 15, l4 = lane >> 4;
    const int bh = blockIdx.x >> 3, qt = blockIdx.x & 7;
    const int qb = qt * 128 + w * 32;

    const bf16* Q  = qg  + (size_t)bh * TT * DH;
    const bf16* Kp = kg  + (size_t)bh * TT * DH;
    const bf16* Vt = vtg + (size_t)bh * DH * TT;

    // Q fragments: rows qb+mi*16+l15, k = kk*32 + l4*8 .. +8
    bf16x8 qf[2][2];
#pragma unroll
    for (int mi = 0; mi < 2; ++mi)
#pragma unroll
        for (int kk = 0; kk < 2; ++kk)
            qf[mi][kk] = *(const bf16x8*)(Q + (size_t)(qb + mi * 16 + l15) * DH + kk * 32 + l4 * 8);

    f32x4 zero = {0.f, 0.f, 0.f, 0.f};
    f32x4 y[2][4];
    float m_[2][4], l_[2][4];
#pragma unroll
    for (int mi = 0; mi < 2; ++mi)
#pragma unroll
        for (int rg = 0; rg < 4; ++rg) { m_[mi][rg] = -1e30f; l_[mi][rg] = 0.f; }
#pragma unroll
    for (int mi = 0; mi < 2; ++mi)
#pragma unroll
        for (int dj = 0; dj < 4; ++dj) y[mi][dj] = zero;

    bf16* myP = &pl[w][0];
    const int ntile = qb / 32 + 1;

    for (int t = 0; t < ntile; ++t) {
        const int t0 = t * 32;
        bf16x8 kf[2][2];
#pragma unroll
        for (int nj = 0; nj < 2; ++nj)
#pragma unroll
            for (int kk = 0; kk < 2; ++kk)
                kf[nj][kk] = *(const bf16x8*)(Kp + (size_t)(t0 + nj * 16 + l15) * DH + kk * 32 + l4 * 8);

        f32x4 s[2][2];
#pragma unroll
        for (int mi = 0; mi < 2; ++mi)
#pragma unroll
            for (int nj = 0; nj < 2; ++nj) {
                f32x4 a = zero;
                a = mfma16(qf[mi][0], kf[nj][0], a);
                a = mfma16(qf[mi][1], kf[nj][1], a);
                s[mi][nj] = a;
            }

        const bool diag = (t == ntile - 1);
#pragma unroll
        for (int mi = 0; mi < 2; ++mi)
#pragma unroll
            for (int nj = 0; nj < 2; ++nj)
#pragma unroll
                for (int rg = 0; rg < 4; ++rg) {
                    float v = s[mi][nj][rg] * 0.125f;
                    if (diag) {
                        int rr = qb + mi * 16 + l4 * 4 + rg;
                        int cc = t0 + nj * 16 + l15;
                        if (cc > rr) v = -1e30f;
                    }
                    s[mi][nj][rg] = v;
                }

        // online softmax per q-row; a row's 32 scores live in 16 lanes x 2 nj at fixed (mi,rg)
#pragma unroll
        for (int mi = 0; mi < 2; ++mi)
#pragma unroll
            for (int rg = 0; rg < 4; ++rg) {
                float mx = fmaxf(s[mi][0][rg], s[mi][1][rg]);
                mx = fmaxf(mx, __shfl_xor(mx, 1));
                mx = fmaxf(mx, __shfl_xor(mx, 2));
                mx = fmaxf(mx, __shfl_xor(mx, 4));
                mx = fmaxf(mx, __shfl_xor(mx, 8));
                float mold = m_[mi][rg];
                float mnew = fmaxf(mold, mx);
                float corr = __expf(mold - mnew);
                m_[mi][rg] = mnew;
                float p0 = __expf(s[mi][0][rg] - mnew);
                float p1 = __expf(s[mi][1][rg] - mnew);
                s[mi][0][rg] = p0; s[mi][1][rg] = p1;
                float rs = p0 + p1;
                rs += __shfl_xor(rs, 1);
                rs += __shfl_xor(rs, 2);
                rs += __shfl_xor(rs, 4);
                rs += __shfl_xor(rs, 8);
                l_[mi][rg] = l_[mi][rg] * corr + rs;
#pragma unroll
                for (int dj = 0; dj < 4; ++dj) y[mi][dj][rg] *= corr;
            }

        // P -> LDS (padded rows), re-read as MFMA A-fragments
#pragma unroll
        for (int mi = 0; mi < 2; ++mi)
#pragma unroll
            for (int nj = 0; nj < 2; ++nj)
#pragma unroll
                for (int rg = 0; rg < 4; ++rg) {
                    int rr = mi * 16 + l4 * 4 + rg;
                    int cc = nj * 16 + l15;
                    myP[rr * 40 + cc] = (bf16)s[mi][nj][rg];
                }
        bf16x8 pa[2];
#pragma unroll
        for (int mi = 0; mi < 2; ++mi)
            pa[mi] = *(const bf16x8*)(myP + (mi * 16 + l15) * 40 + l4 * 8);

        bf16x8 vf[4];
#pragma unroll
        for (int dj = 0; dj < 4; ++dj)
            vf[dj] = *(const bf16x8*)(Vt + (size_t)(dj * 16 + l15) * TT + t0 + l4 * 8);

#pragma unroll
        for (int mi = 0; mi < 2; ++mi)
#pragma unroll
            for (int dj = 0; dj < 4; ++dj)
                y[mi][dj] = mfma16(pa[mi], vf[dj], y[mi][dj]);
    }

    const int b = bh >> 3, h = bh & 7;
#pragma unroll
    for (int mi = 0; mi < 2; ++mi)
#pragma unroll
        for (int rg = 0; rg < 4; ++rg) {
            float inv = 1.0f / l_[mi][rg];
#pragma unroll
            for (int dj = 0; dj < 4; ++dj) {
                int rr = qb + mi * 16 + l4 * 4 + rg;
                int cc = dj * 16 + l15;
                float v = y[mi][dj][rg] * inv;
                yb[((size_t)b * TT + rr) * CC + h * DH + cc] = (bf16)v;
            }
        }
}

// ---------------- launch ----------------
extern "C" void kernel_launch(void* const* d_in, const int* in_sizes, int n_in,
                              void* d_out, int out_size, void* d_ws, size_t ws_size,
                              hipStream_t stream)
{
    const float* x    = (const float*)d_in[0];   // [16,1024,512]
    const float* wqkv = (const float*)d_in[1];   // [512,1536]
    const float* wout = (const float*)d_in[2];   // [512,512]
    float* out = (float*)d_out;                  // [16,1024,512] fp32

    const size_t NX = (size_t)BB * TT * CC;      // 8,388,608 elems
    bf16* p   = (bf16*)d_ws;
    bf16* Xb  = p;  p += NX;                     // bf16 x  (reused as Yb after GEMM1)
    bf16* Wqt = p;  p += (size_t)(3 * CC) * CC;  // Wqkv^T [1536][512]
    bf16* Wot = p;  p += (size_t)CC * CC;        // Wout^T [512][512]
    bf16* Qb  = p;  p += NX;                     // [128][1024][64]
    bf16* Kb  = p;  p += NX;
    bf16* Vtb = p;  p += NX;                     // [128][64][1024]
    bf16* Yb  = Xb;                              // alias: Xb dead after GEMM1

    // dtype conversions
    k_cvt  <<<(int)(NX / 4 / 256), 256, 0, stream>>>(x, Xb, (int)NX);
    k_cvt_t<<<(3 * CC * CC + 255) / 256, 256, 0, stream>>>(wqkv, Wqt, CC, 3 * CC);
    k_cvt_t<<<(CC * CC + 255) / 256, 256, 0, stream>>>(wout, Wot, CC, CC);

    // QKV projection with scatter into Q / K / V^T
    k_gemm_bt<1><<<(BB * TT / 128) * (3 * CC / 128), 256, 0, stream>>>(
        Xb, Wqt, BB * TT, 3 * CC, CC, nullptr, Qb, Kb, Vtb);

    // causal flash attention -> Yb [B*T][C]
    k_attn<<<BB * HH * (TT / 128), 256, 0, stream>>>(Qb, Kb, Vtb, Yb);

    // output projection -> fp32 out
    k_gemm_bt<0><<<(BB * TT / 128) * (CC / 128), 256, 0, stream>>>(
        Yb, Wot, BB * TT, CC, CC, out, nullptr, nullptr, nullptr);
}

// Round 2
// 170.216 us; speedup vs baseline: 1.4315x; 1.4315x over previous
//
#include <hip/hip_runtime.h>
#include <hip/hip_bf16.h>

typedef __bf16 bf16;
typedef __bf16 bf16x4 __attribute__((ext_vector_type(4)));
typedef __bf16 bf16x8 __attribute__((ext_vector_type(8)));
typedef float  f32x4  __attribute__((ext_vector_type(4)));

// Problem constants: B=16, T=1024, C=512, H=8, Dh=64
#define BB 16
#define TT 1024
#define CC 512
#define HH 8
#define DH 64

__device__ __forceinline__ void gload16(const void* gsrc, void* ldst) {
    __builtin_amdgcn_global_load_lds(
        (const __attribute__((address_space(1))) void*)gsrc,
        (__attribute__((address_space(3))) void*)ldst, 16, 0, 0);
}

__device__ __forceinline__ f32x4 mfma16(bf16x8 a, bf16x8 b, f32x4 c) {
    return __builtin_amdgcn_mfma_f32_16x16x32_bf16(a, b, c, 0, 0, 0);
}

// ---------------- conversion kernels ----------------
__global__ void k_cvt(const float* __restrict__ src, bf16* __restrict__ dst, int n) {
    int i = (blockIdx.x * blockDim.x + threadIdx.x) * 4;
    if (i < n) {
        float4 v = *(const float4*)(src + i);
        bf16x4 o = { (bf16)v.x, (bf16)v.y, (bf16)v.z, (bf16)v.w };
        *(bf16x4*)(dst + i) = o;
    }
}

__global__ void k_cvt_t(const float* __restrict__ src, bf16* __restrict__ dst, int K, int N) {
    int idx = blockIdx.x * blockDim.x + threadIdx.x;
    if (idx < K * N) {
        int k = idx / N, n = idx - k * N;
        dst[(size_t)n * K + k] = (bf16)src[idx];
    }
}

// ---------------- GEMM: C[M,N] = A[M,K] * Bt[N,K]^T (m97 structure) ----------------
template<int MODE>
__global__ __launch_bounds__(256)
void k_gemm_bt(const bf16* __restrict__ A, const bf16* __restrict__ Bt,
               int M, int N, int K,
               float* __restrict__ outF,
               bf16* __restrict__ qb, bf16* __restrict__ kb, bf16* __restrict__ vtb)
{
    __shared__ bf16 sA[128 * 32];
    __shared__ bf16 sB[128 * 32];
    const int tid  = threadIdx.x;
    const int wid  = tid >> 6;
    const int lane = tid & 63;
    const int l15  = lane & 15, l4 = lane >> 4;

    const int nNt = N >> 7;
    const int mt  = blockIdx.x / nNt;
    const int nt  = blockIdx.x - mt * nNt;
    const int m0  = mt << 7, n0 = nt << 7;
    const int wr  = (wid >> 1) * 64, wc = (wid & 1) * 64;

    f32x4 zero = {0.f, 0.f, 0.f, 0.f};
    f32x4 acc[4][4];
#pragma unroll
    for (int i = 0; i < 4; ++i)
#pragma unroll
        for (int j = 0; j < 4; ++j) acc[i][j] = zero;

    const int soff0 = wid * 1024;
    const int soff1 = soff0 + 512;
    const int e0 = soff0 + lane * 8;
    const int e1 = soff1 + lane * 8;
    const int r0 = e0 >> 5, c0 = e0 & 31;
    const int r1 = e1 >> 5, c1 = e1 & 31;

    for (int k0 = 0; k0 < K; k0 += 32) {
        gload16(A  + (size_t)(m0 + r0) * K + k0 + c0, sA + soff0);
        gload16(A  + (size_t)(m0 + r1) * K + k0 + c1, sA + soff1);
        gload16(Bt + (size_t)(n0 + r0) * K + k0 + c0, sB + soff0);
        gload16(Bt + (size_t)(n0 + r1) * K + k0 + c1, sB + soff1);
        __syncthreads();
        bf16x8 af[4], bfr[4];
#pragma unroll
        for (int i = 0; i < 4; ++i)
            af[i] = *(const bf16x8*)(sA + (wr + i * 16 + l15) * 32 + l4 * 8);
#pragma unroll
        for (int j = 0; j < 4; ++j)
            bfr[j] = *(const bf16x8*)(sB + (wc + j * 16 + l15) * 32 + l4 * 8);
#pragma unroll
        for (int i = 0; i < 4; ++i)
#pragma unroll
            for (int j = 0; j < 4; ++j)
                acc[i][j] = mfma16(af[i], bfr[j], acc[i][j]);
        __syncthreads();
    }

#pragma unroll
    for (int i = 0; i < 4; ++i) {
#pragma unroll
        for (int j = 0; j < 4; ++j) {
#pragma unroll
            for (int rg = 0; rg < 4; ++rg) {
                int rm = m0 + wr + i * 16 + l4 * 4 + rg;
                int cn = n0 + wc + j * 16 + l15;
                float v = acc[i][j][rg];
                if (MODE == 0) {
                    outF[(size_t)rm * N + cn] = v;
                } else {
                    int b = rm >> 10, t = rm & 1023;
                    int s = cn >> 9, h = (cn >> 6) & 7, d = cn & 63;
                    size_t bh = (size_t)(b * HH + h);
                    bf16 bv = (bf16)v;
                    if (s == 0)      qb [(bh * TT + t) * DH + d] = bv;
                    else if (s == 1) kb [(bh * TT + t) * DH + d] = bv;
                    else             vtb[(bh * DH + d) * TT + t] = bv;
                }
            }
        }
    }
}

// ---------------- flash attention v2 (causal, swapped QK^T, balanced) ----------------
// grid: 2048 blocks x 64 threads (1 wave). Wave handles q-units {p, 31-p} of one bh
// -> uniform 33 KV-tiles per wave. XCD-clustered bh mapping.
__global__ __launch_bounds__(64)
void k_attn(const bf16* __restrict__ qg, const bf16* __restrict__ kg,
            const bf16* __restrict__ vtg, bf16* __restrict__ yb)
{
    __shared__ bf16  sP[32 * 40];   // P tile [32 q][32 k], rows padded to 40
    __shared__ float sC[32];        // per-q rescale factor
    __shared__ float sL[32];        // per-q final denom
    const int lane = threadIdx.x & 63;
    const int l15 = lane & 15, l4 = lane >> 4;

    // block -> (bh, pair): XCD x gets bh [16x, 16x+16)
    const int bid  = blockIdx.x;
    const int x    = bid & 7;
    const int jj   = bid >> 3;            // 0..255
    const int bh   = x * 16 + (jj >> 4);  // 0..127
    const int pair = jj & 15;             // 0..15

    const bf16* Q  = qg  + (size_t)bh * TT * DH;
    const bf16* Kp = kg  + (size_t)bh * TT * DH;
    const bf16* Vt = vtg + (size_t)bh * DH * TT;
    const int b = bh >> 3, h = bh & 7;

    const f32x4 zero = {0.f, 0.f, 0.f, 0.f};

    for (int up = 0; up < 2; ++up) {
        const int u  = up ? (31 - pair) : pair;   // q-unit index 0..31
        const int qb = u * 32;
        const int nt = u + 1;                     // causal KV tiles

        // Q fragments (used as MFMA B operand): row q = qb+mi*16+l15
        bf16x8 qf[2][2];
#pragma unroll
        for (int mi = 0; mi < 2; ++mi)
#pragma unroll
            for (int kk = 0; kk < 2; ++kk)
                qf[mi][kk] = *(const bf16x8*)(Q + (size_t)(qb + mi * 16 + l15) * DH + kk * 32 + l4 * 8);

        f32x4 y[2][4];
        float m_[2], l_[2];
#pragma unroll
        for (int mi = 0; mi < 2; ++mi) {
            m_[mi] = -1e30f; l_[mi] = 0.f;
#pragma unroll
            for (int dj = 0; dj < 4; ++dj) y[mi][dj] = zero;
        }

        bf16x8 kfA[2][2], vfA[4], kfB[2][2], vfB[4];

        auto loadK = [&](bf16x8 (&kf)[2][2], int t) {
            const int t0 = t * 32;
#pragma unroll
            for (int nj = 0; nj < 2; ++nj)
#pragma unroll
                for (int kk = 0; kk < 2; ++kk)
                    kf[nj][kk] = *(const bf16x8*)(Kp + (size_t)(t0 + nj * 16 + l15) * DH + kk * 32 + l4 * 8);
        };
        auto loadV = [&](bf16x8 (&vf)[4], int t) {
            const int t0 = t * 32;
#pragma unroll
            for (int dj = 0; dj < 4; ++dj)
                vf[dj] = *(const bf16x8*)(Vt + (size_t)(dj * 16 + l15) * TT + t0 + l4 * 8);
        };

        auto step = [&](bf16x8 (&kf)[2][2], bf16x8 (&vf)[4], int t) {
            const int t0 = t * 32;
            // S^T = K * Q^T : s[mi][nj] rows k = t0+nj*16+l4*4+rg, col q = qb+mi*16+l15
            f32x4 s[2][2];
#pragma unroll
            for (int mi = 0; mi < 2; ++mi)
#pragma unroll
                for (int nj = 0; nj < 2; ++nj) {
                    f32x4 a = mfma16(kf[nj][0], qf[mi][0], zero);
                    s[mi][nj] = mfma16(kf[nj][1], qf[mi][1], a);
                }

            const bool diag = (t == nt - 1);
#pragma unroll
            for (int mi = 0; mi < 2; ++mi)
#pragma unroll
                for (int nj = 0; nj < 2; ++nj)
#pragma unroll
                    for (int rg = 0; rg < 4; ++rg) {
                        float v = s[mi][nj][rg] * 0.125f;
                        if (diag) {
                            int kk = nj * 16 + l4 * 4 + rg;   // k within tile (t0 == qb here)
                            int qq = mi * 16 + l15;           // q within unit
                            if (kk > qq) v = -1e30f;
                        }
                        s[mi][nj][rg] = v;
                    }

            // online softmax per q (col of S^T): 8 in-lane values x 4 lanes (stride 16)
#pragma unroll
            for (int mi = 0; mi < 2; ++mi) {
                float mx = s[mi][0][0];
#pragma unroll
                for (int nj = 0; nj < 2; ++nj)
#pragma unroll
                    for (int rg = 0; rg < 4; ++rg) mx = fmaxf(mx, s[mi][nj][rg]);
                mx = fmaxf(mx, __shfl_xor(mx, 16));
                mx = fmaxf(mx, __shfl_xor(mx, 32));
                float mold = m_[mi];
                float mnew = fmaxf(mold, mx);
                float corr = __expf(mold - mnew);
                m_[mi] = mnew;
                float rs = 0.f;
#pragma unroll
                for (int nj = 0; nj < 2; ++nj) {
                    bf16x4 pk;
#pragma unroll
                    for (int rg = 0; rg < 4; ++rg) {
                        float p = __expf(s[mi][nj][rg] - mnew);
                        rs += p;
                        pk[rg] = (bf16)p;
                    }
                    *(bf16x4*)(sP + (mi * 16 + l15) * 40 + nj * 16 + l4 * 4) = pk;
                }
                rs += __shfl_xor(rs, 16);
                rs += __shfl_xor(rs, 32);
                l_[mi] = l_[mi] * corr + rs;
                if (l4 == 0) sC[mi * 16 + l15] = corr;
            }

            // P back as A-fragments + per-row rescale (same wave: compiler orders LDS)
            bf16x8 pa[2];
            f32x4  cv[2];
#pragma unroll
            for (int mi = 0; mi < 2; ++mi) {
                pa[mi] = *(const bf16x8*)(sP + (mi * 16 + l15) * 40 + l4 * 8);
                cv[mi] = *(const f32x4*)(sC + mi * 16 + l4 * 4);
            }
#pragma unroll
            for (int mi = 0; mi < 2; ++mi)
#pragma unroll
                for (int dj = 0; dj < 4; ++dj) {
                    f32x4 acc = y[mi][dj] * cv[mi];
                    y[mi][dj] = mfma16(pa[mi], vf[dj], acc);
                }
        };

        // software-pipelined loop, manual 2-body rotation (static frag indices)
        loadK(kfA, 0);
        loadV(vfA, 0);
        int t = 0;
        while (true) {
            if (t + 1 < nt) { loadK(kfB, t + 1); loadV(vfB, t + 1); }
            step(kfA, vfA, t);
            ++t; if (t >= nt) break;
            if (t + 1 < nt) { loadK(kfA, t + 1); loadV(vfA, t + 1); }
            step(kfB, vfB, t);
            ++t; if (t >= nt) break;
        }

        // epilogue: redistribute denom to row layout, normalize, store
        if (l4 == 0) { sL[l15] = l_[0]; sL[16 + l15] = l_[1]; }
        f32x4 lv[2];
#pragma unroll
        for (int mi = 0; mi < 2; ++mi)
            lv[mi] = *(const f32x4*)(sL + mi * 16 + l4 * 4);
#pragma unroll
        for (int mi = 0; mi < 2; ++mi)
#pragma unroll
            for (int rg = 0; rg < 4; ++rg) {
                float inv = 1.0f / lv[mi][rg];
                int rr = qb + mi * 16 + l4 * 4 + rg;
#pragma unroll
                for (int dj = 0; dj < 4; ++dj) {
                    int cc = dj * 16 + l15;
                    yb[((size_t)b * TT + rr) * CC + h * DH + cc] = (bf16)(y[mi][dj][rg] * inv);
                }
            }
    }
}

// ---------------- launch ----------------
extern "C" void kernel_launch(void* const* d_in, const int* in_sizes, int n_in,
                              void* d_out, int out_size, void* d_ws, size_t ws_size,
                              hipStream_t stream)
{
    const float* x    = (const float*)d_in[0];   // [16,1024,512]
    const float* wqkv = (const float*)d_in[1];   // [512,1536]
    const float* wout = (const float*)d_in[2];   // [512,512]
    float* out = (float*)d_out;                  // [16,1024,512] fp32

    const size_t NX = (size_t)BB * TT * CC;
    bf16* p   = (bf16*)d_ws;
    bf16* Xb  = p;  p += NX;
    bf16* Wqt = p;  p += (size_t)(3 * CC) * CC;
    bf16* Wot = p;  p += (size_t)CC * CC;
    bf16* Qb  = p;  p += NX;
    bf16* Kb  = p;  p += NX;
    bf16* Vtb = p;  p += NX;
    bf16* Yb  = Xb;                              // alias: Xb dead after GEMM1

    k_cvt  <<<(int)(NX / 4 / 256), 256, 0, stream>>>(x, Xb, (int)NX);
    k_cvt_t<<<(3 * CC * CC + 255) / 256, 256, 0, stream>>>(wqkv, Wqt, CC, 3 * CC);
    k_cvt_t<<<(CC * CC + 255) / 256, 256, 0, stream>>>(wout, Wot, CC, CC);

    k_gemm_bt<1><<<(BB * TT / 128) * (3 * CC / 128), 256, 0, stream>>>(
        Xb, Wqt, BB * TT, 3 * CC, CC, nullptr, Qb, Kb, Vtb);

    k_attn<<<BB * HH * 16, 64, 0, stream>>>(Qb, Kb, Vtb, Yb);

    k_gemm_bt<0><<<(BB * TT / 128) * (CC / 128), 256, 0, stream>>>(
        Yb, Wot, BB * TT, CC, CC, out, nullptr, nullptr, nullptr);
}